// Round 7
// baseline (412.463 us; speedup 1.0000x reference)
//
#include <hip/hip_runtime.h>
#include <cstdint>

#define NPT   4096
#define NBAT  4
#define NS    32
#define R2C   0.04f
#define NSMP  524288          // B*N*ns total samples

// ---- workspace layout (float offsets) ----
#define OFF_XYZ4 0            // B*N float4 (x,y,z,|p|^2)        65536
#define OFF_F1S  65536        // B*N*64 layer1 feature part      1048576
#define OFF_PT   1114112      // B*N*128 pooled (n-major)        2097152
#define OFF_WX   3211264      // 64*4 xyz weights *s1            256
#define OFF_W1T  3211520      // 64x64 W1 feat [c][co]*s1        4096
#define OFF_W2T  3215616      // 64x64 W2^T*s2 [c][o]            4096
#define OFF_W3T  3219712      // 64x128 W3^T*s3 [c][o]           8192
#define OFF_IDX  3227904      // B*N*32 int32                    524288
#define OFF_H2   3752192      // 16 planes x NSMP x float4       33554432
#define WS_NEED  ((size_t)(OFF_H2 + 33554432) * 4)   // 149226496 B

// ---------------- weight prep ----------------
__global__ __launch_bounds__(256) void k_prep(
    const float* __restrict__ W1, const float* __restrict__ s1,
    const float* __restrict__ W2, const float* __restrict__ s2,
    const float* __restrict__ W3, const float* __restrict__ s3,
    float* __restrict__ ws) {
  int i = blockIdx.x * 256 + threadIdx.x;          // 0..8191
  if (i < 256) { int c = i >> 2, d = i & 3;
    ws[OFF_WX + i] = (d < 3) ? W1[c * 67 + d] * s1[c] : 0.f; }
  if (i < 4096) { int c = i >> 6, co = i & 63;
    ws[OFF_W1T + c * 64 + co] = W1[co * 67 + 3 + c] * s1[co]; }
  if (i < 4096) { int c = i >> 6, o = i & 63;
    ws[OFF_W2T + c * 64 + o] = W2[o * 64 + c] * s2[o]; }
  if (i < 8192) { int c = i >> 7, o = i & 127;
    ws[OFF_W3T + c * 128 + o] = W3[o * 64 + c] * s3[o]; }
}

// ---------------- xyz -> float4(x,y,z,sq); np rounding order, no fma ----------------
__global__ __launch_bounds__(256) void k_xyz4(const float* __restrict__ xyz,
                                              float* __restrict__ ws) {
  int i = blockIdx.x * 256 + threadIdx.x;          // 0..16383
  float x = xyz[i * 3], y = xyz[i * 3 + 1], z = xyz[i * 3 + 2];
  float sq = __fadd_rn(__fadd_rn(__fmul_rn(x, x), __fmul_rn(y, y)), __fmul_rn(z, z));
  ((float4*)(ws + OFF_XYZ4))[i] = make_float4(x, y, z, sq);
}

// ---------------- ball query: wave per center, LDS-staged points ----------------
__global__ __launch_bounds__(256, 2) void k_bq(const float* __restrict__ ws,
                                               int* __restrict__ idxo) {
  __shared__ float4 sxb[NPT / 2];                  // 32 KB
  int tid = threadIdx.x, lane = tid & 63;
  int center = blockIdx.x * 4 + (tid >> 6);        // 0..16383
  int b = center >> 12, n = center & 4095;
  const float4* xb = (const float4*)(ws + OFF_XYZ4) + b * NPT;
  float4 cp = xb[n];
  unsigned long long lmask = (1ull << lane) - 1ull;
  int cnt = 0, first = 0;
#pragma unroll 1
  for (int half = 0; half < 2; ++half) {
    __syncthreads();
    for (int i = tid; i < NPT / 2; i += 256) sxb[i] = xb[half * (NPT / 2) + i];
    __syncthreads();
    if (cnt >= NS) continue;                       // wave-uniform skip
    float4 p = sxb[lane];
#pragma unroll 1
    for (int ch = 0; ch < 32; ++ch) {
      float4 pn = sxb[((ch + 1) & 31) * 64 + lane];   // prefetch next chunk
      float dot = __fadd_rn(__fadd_rn(__fmul_rn(p.x, cp.x), __fmul_rn(p.y, cp.y)),
                            __fmul_rn(p.z, cp.z));
      float d2 = __fsub_rn(__fadd_rn(cp.w, p.w), __fmul_rn(2.f, dot));
      bool hit = d2 <= R2C;
      unsigned long long mk = __ballot(hit);
      int m = half * (NPT / 2) + ch * 64 + lane;
      if (mk) {
        if (cnt == 0) first = m - lane + __builtin_ctzll(mk);
        int pos = cnt + (int)__popcll(mk & lmask);
        if (hit && pos < NS) idxo[center * NS + pos] = m;
        cnt += (int)__popcll(mk);
        if (cnt >= NS) break;                      // uniform
      }
      p = pn;
    }
  }
  if (cnt < NS && lane >= cnt && lane < NS) idxo[center * NS + lane] = first;
}

// ---------------- F1s = (W1_feat @ features)*s1 + t1, [b][m][co] ----------------
__global__ __launch_bounds__(256, 4) void k_f1(
    const float* __restrict__ feat, const float* __restrict__ t1,
    const float* __restrict__ w1t, float* __restrict__ f1out) {
  int gid = blockIdx.x * 256 + threadIdx.x;        // 0..65535
  int chunk = gid >> 14, ml = gid & 16383;
  int b = ml >> 12, m = ml & 4095;
  float acc[16];
#pragma unroll
  for (int j = 0; j < 16; ++j) acc[j] = t1[chunk * 16 + j];
#pragma unroll
  for (int c = 0; c < 64; ++c) {
    float f = feat[(b * 64 + c) * NPT + m];
#pragma unroll
    for (int j = 0; j < 16; ++j)
      acc[j] = fmaf(w1t[c * 64 + chunk * 16 + j], f, acc[j]);
  }
  float* o = f1out + (size_t)(b * NPT + m) * 64 + chunk * 16;
#pragma unroll
  for (int j = 0; j < 4; ++j)
    ((float4*)o)[j] = make_float4(acc[4 * j], acc[4 * j + 1], acc[4 * j + 2], acc[4 * j + 3]);
}

// ---------------- layer1+layer2: lane = sample, h2 -> 16 float4-planes ----------------
// amdgpu_waves_per_eu(3,4): cap occupancy target so ~92 live floats stay in arch
// VGPRs (512/4=128 budget). Round-5 evidence: without the max-bound the allocator
// targeted ~9 waves/EU and banked h1/acc into AGPRs (VGPR_Count=56, VALU 2.2x).
__global__ __attribute__((amdgpu_waves_per_eu(3, 4))) __launch_bounds__(256) void k_l2(
    const float* __restrict__ ws_c, const int* __restrict__ idxp,
    const float* __restrict__ t2, float* __restrict__ h2out) {
  int s = blockIdx.x * 256 + threadIdx.x;          // 0..524287
  int center = s >> 5;
  int b = center >> 12, n = center & 4095;
  int m = idxp[s];
  const float4* xb = (const float4*)(ws_c + OFF_XYZ4) + b * NPT;
  float4 cp = xb[n], np = xb[m];
  float rx = np.x - cp.x, ry = np.y - cp.y, rz = np.z - cp.z;

  const float4* f1 = (const float4*)(ws_c + OFF_F1S + (size_t)(b * NPT + m) * 64);
  const float* wx = ws_c + OFF_WX;
  float h1[64];
#pragma unroll
  for (int i = 0; i < 16; ++i) {
    float4 q = f1[i];
    int c = 4 * i;
    h1[c + 0] = fmaxf(fmaf(wx[(c + 0) * 4 + 2], rz, fmaf(wx[(c + 0) * 4 + 1], ry, fmaf(wx[(c + 0) * 4], rx, q.x))), 0.f);
    h1[c + 1] = fmaxf(fmaf(wx[(c + 1) * 4 + 2], rz, fmaf(wx[(c + 1) * 4 + 1], ry, fmaf(wx[(c + 1) * 4], rx, q.y))), 0.f);
    h1[c + 2] = fmaxf(fmaf(wx[(c + 2) * 4 + 2], rz, fmaf(wx[(c + 2) * 4 + 1], ry, fmaf(wx[(c + 2) * 4], rx, q.z))), 0.f);
    h1[c + 3] = fmaxf(fmaf(wx[(c + 3) * 4 + 2], rz, fmaf(wx[(c + 3) * 4 + 1], ry, fmaf(wx[(c + 3) * 4], rx, q.w))), 0.f);
  }

  const float* W2T = ws_c + OFF_W2T;
#pragma unroll
  for (int ch = 0; ch < 4; ++ch) {
    float acc[16];
#pragma unroll
    for (int j = 0; j < 16; ++j) acc[j] = t2[ch * 16 + j];
#pragma unroll
    for (int c = 0; c < 64; ++c) {
#pragma unroll
      for (int j = 0; j < 16; ++j)
        acc[j] = fmaf(W2T[c * 64 + ch * 16 + j], h1[c], acc[j]);
    }
#pragma unroll
    for (int q = 0; q < 4; ++q) {
      float4 v = make_float4(fmaxf(acc[4 * q], 0.f), fmaxf(acc[4 * q + 1], 0.f),
                             fmaxf(acc[4 * q + 2], 0.f), fmaxf(acc[4 * q + 3], 0.f));
      ((float4*)h2out)[(size_t)(4 * ch + q) * NSMP + s] = v;   // coalesced plane store
    }
  }
}

// ---------------- layer3 + relu + pool over 32 samples ----------------
__global__ __attribute__((amdgpu_waves_per_eu(3, 4))) __launch_bounds__(256) void k_l3(
    const float* __restrict__ h2in, const float* __restrict__ ws_c,
    const float* __restrict__ t3, float* __restrict__ pooledT) {
  int s = blockIdx.x * 256 + threadIdx.x;          // 0..524287
  int center = s >> 5, k = s & 31;
  float h2[64];
#pragma unroll
  for (int p = 0; p < 16; ++p) {
    float4 q = ((const float4*)h2in)[(size_t)p * NSMP + s];    // coalesced plane load
    h2[4 * p] = q.x; h2[4 * p + 1] = q.y; h2[4 * p + 2] = q.z; h2[4 * p + 3] = q.w;
  }
  const float* W3T = ws_c + OFF_W3T;
  float* op = pooledT + (size_t)center * 128;
#pragma unroll
  for (int ch = 0; ch < 8; ++ch) {
    float acc[16];
#pragma unroll
    for (int j = 0; j < 16; ++j) acc[j] = t3[ch * 16 + j];
#pragma unroll
    for (int c = 0; c < 64; ++c) {
#pragma unroll
      for (int j = 0; j < 16; ++j)
        acc[j] = fmaf(W3T[c * 128 + ch * 16 + j], h2[c], acc[j]);
    }
#pragma unroll
    for (int j = 0; j < 16; ++j) {
      float v = fmaxf(acc[j], 0.f);
      v = fmaxf(v, __shfl_xor(v, 1));
      v = fmaxf(v, __shfl_xor(v, 2));
      v = fmaxf(v, __shfl_xor(v, 4));
      v = fmaxf(v, __shfl_xor(v, 8));
      v = fmaxf(v, __shfl_xor(v, 16));
      acc[j] = v;
    }
    if (k == 0) {
#pragma unroll
      for (int q = 0; q < 4; ++q)
        ((float4*)(op + ch * 16))[q] = make_float4(acc[4 * q], acc[4 * q + 1],
                                                   acc[4 * q + 2], acc[4 * q + 3]);
    }
  }
}

// ---------------- fallback fused MLP (round-3 passing version) ----------------
__global__ __attribute__((amdgpu_waves_per_eu(2, 2))) __launch_bounds__(256) void k_main(
    const float* __restrict__ ws_c, const int* __restrict__ idx,
    const float* __restrict__ t2, const float* __restrict__ t3,
    float* __restrict__ pooledT) {
  int tid = threadIdx.x, lane = tid & 63;
  int gw = blockIdx.x * 4 + (tid >> 6);
  int center = gw * 2 + (lane >> 5);
  int b = center >> 12, n = center & 4095;
  int k = lane & 31;
  int m = idx[center * NS + k];
  const float4* xb = (const float4*)(ws_c + OFF_XYZ4) + b * NPT;
  float4 cp = xb[n], np = xb[m];
  float rx = np.x - cp.x, ry = np.y - cp.y, rz = np.z - cp.z;
  const float4* f1 = (const float4*)(ws_c + OFF_F1S + (size_t)(b * NPT + m) * 64);
  float h1[64];
#pragma unroll
  for (int i = 0; i < 16; ++i) {
    float4 q = f1[i];
    h1[4 * i] = q.x; h1[4 * i + 1] = q.y; h1[4 * i + 2] = q.z; h1[4 * i + 3] = q.w;
  }
  const float* wx = ws_c + OFF_WX;
#pragma unroll
  for (int c = 0; c < 64; ++c) {
    float t = fmaf(wx[c * 4 + 2], rz, fmaf(wx[c * 4 + 1], ry, fmaf(wx[c * 4], rx, h1[c])));
    h1[c] = fmaxf(t, 0.f);
  }
  float h2[64];
  const float* W2T = ws_c + OFF_W2T;
#pragma unroll
  for (int ch = 0; ch < 2; ++ch) {
    float acc[32];
#pragma unroll
    for (int j = 0; j < 32; ++j) acc[j] = t2[ch * 32 + j];
#pragma unroll
    for (int c = 0; c < 64; ++c) {
#pragma unroll
      for (int j = 0; j < 32; ++j)
        acc[j] = fmaf(W2T[c * 64 + ch * 32 + j], h1[c], acc[j]);
    }
#pragma unroll
    for (int j = 0; j < 32; ++j) h2[ch * 32 + j] = fmaxf(acc[j], 0.f);
  }
  const float* W3T = ws_c + OFF_W3T;
  float* op = pooledT + (size_t)center * 128;
#pragma unroll
  for (int ch = 0; ch < 4; ++ch) {
    float acc[32];
#pragma unroll
    for (int j = 0; j < 32; ++j) acc[j] = t3[ch * 32 + j];
#pragma unroll
    for (int c = 0; c < 64; ++c) {
#pragma unroll
      for (int j = 0; j < 32; ++j)
        acc[j] = fmaf(W3T[c * 128 + ch * 32 + j], h2[c], acc[j]);
    }
#pragma unroll
    for (int j = 0; j < 32; ++j) {
      float v = fmaxf(acc[j], 0.f);
      v = fmaxf(v, __shfl_xor(v, 1));
      v = fmaxf(v, __shfl_xor(v, 2));
      v = fmaxf(v, __shfl_xor(v, 4));
      v = fmaxf(v, __shfl_xor(v, 8));
      v = fmaxf(v, __shfl_xor(v, 16));
      acc[j] = v;
    }
    if (k == 0) {
#pragma unroll
      for (int i = 0; i < 8; ++i)
        ((float4*)(op + ch * 32))[i] =
            make_float4(acc[4 * i], acc[4 * i + 1], acc[4 * i + 2], acc[4 * i + 3]);
    }
  }
}

// ---------------- (B,N,128) -> (B,128,N) transpose ----------------
__global__ __launch_bounds__(256) void k_tr(const float* __restrict__ pooledT,
                                            float* __restrict__ out) {
  __shared__ float tile[64][65];
  int b = blockIdx.z;
  int o0 = blockIdx.y * 64, n0 = blockIdx.x * 64;
  int tx = threadIdx.x & 63, ty = threadIdx.x >> 6;
#pragma unroll
  for (int j = 0; j < 16; ++j) {
    int r = j * 4 + ty;
    tile[r][tx] = pooledT[(size_t)(b * NPT + n0 + r) * 128 + o0 + tx];
  }
  __syncthreads();
#pragma unroll
  for (int j = 0; j < 16; ++j) {
    int r = j * 4 + ty;
    out[(size_t)(b * 128 + o0 + r) * NPT + n0 + tx] = tile[tx][r];
  }
}

extern "C" void kernel_launch(void* const* d_in, const int* in_sizes, int n_in,
                              void* d_out, int out_size, void* d_ws, size_t ws_size,
                              hipStream_t stream) {
  const float* xyz = (const float*)d_in[0];
  const float* feat = (const float*)d_in[1];
  const float* W1 = (const float*)d_in[2];
  const float* s1 = (const float*)d_in[3];
  const float* t1 = (const float*)d_in[4];
  const float* W2 = (const float*)d_in[5];
  const float* s2 = (const float*)d_in[6];
  const float* t2 = (const float*)d_in[7];
  const float* W3 = (const float*)d_in[8];
  const float* s3 = (const float*)d_in[9];
  const float* t3 = (const float*)d_in[10];
  float* ws = (float*)d_ws;
  int* idxp = (int*)(ws + OFF_IDX);
  float* out = (float*)d_out;

  hipMemcpyAsync(out, xyz, (size_t)NBAT * NPT * 3 * sizeof(float),
                 hipMemcpyDeviceToDevice, stream);

  k_prep<<<32, 256, 0, stream>>>(W1, s1, W2, s2, W3, s3, ws);
  k_xyz4<<<64, 256, 0, stream>>>(xyz, ws);
  k_bq<<<4096, 256, 0, stream>>>(ws, idxp);
  k_f1<<<256, 256, 0, stream>>>(feat, t1, ws + OFF_W1T, ws + OFF_F1S);
  if (ws_size >= WS_NEED) {                        // host-constant branch: graph-safe
    k_l2<<<2048, 256, 0, stream>>>(ws, idxp, t2, ws + OFF_H2);
    k_l3<<<2048, 256, 0, stream>>>(ws + OFF_H2, ws, t3, ws + OFF_PT);
  } else {
    k_main<<<2048, 256, 0, stream>>>(ws, idxp, t2, t3, ws + OFF_PT);
  }
  k_tr<<<dim3(64, 2, 4), 256, 0, stream>>>(ws + OFF_PT, out + NBAT * NPT * 3);
}

// Round 8
// 247.421 us; speedup vs baseline: 1.6671x; 1.6671x over previous
//
#include <hip/hip_runtime.h>
#include <cstdint>

#define NPT   4096
#define NBAT  4
#define NS    32
#define R2C   0.04f

// ---- workspace layout (float offsets) ----
#define OFF_XYZ4 0            // B*N float4 (x,y,z,|p|^2)        65536
#define OFF_F1S  65536        // B*N*64 layer1 feature part      1048576
#define OFF_PT   1114112      // B*N*128 pooled (n-major)        2097152
#define OFF_WX   3211264      // 64*4 xyz weights *s1            256
#define OFF_W1T  3211520      // 64x64 W1 feat [c][co]*s1        4096
#define OFF_IDX  3227904      // B*N*32 int32                    524288
#define OFF_W2PH 3752192      // ushort[4096]: W2^T*s2 hi        (2048 f)
#define OFF_W2PL 3754240      // ushort[4096]: lo                (2048 f)
#define OFF_W3PH 3756288      // ushort[8192]: W3^T*s3 hi        (4096 f)
#define OFF_W3PL 3760384      // ushort[8192]: lo                (4096 f)

typedef __attribute__((ext_vector_type(8))) short bf16x8;
typedef __attribute__((ext_vector_type(4))) float f32x4;

__device__ __host__ inline unsigned short f2bf(float x) {
  unsigned u = __builtin_bit_cast(unsigned, x);
  return (unsigned short)((u + 0x7FFFu + ((u >> 16) & 1u)) >> 16);
}
__device__ inline float bf2f(unsigned short h) {
  return __uint_as_float(((unsigned)h) << 16);
}

// XOR-swizzled LDS addressing: [64 rows][64 ushorts]; 16B-granular xor of row
#define SWZ(row, us) (((row) << 6) + ((us) ^ (((row) & 7) << 3)))

// ---------------- weight prep: fp32 aux + bf16 hi/lo splits ----------------
__global__ __launch_bounds__(256) void k_prep(
    const float* __restrict__ W1, const float* __restrict__ s1,
    const float* __restrict__ W2, const float* __restrict__ s2,
    const float* __restrict__ W3, const float* __restrict__ s3,
    float* __restrict__ ws) {
  int i = blockIdx.x * 256 + threadIdx.x;          // 0..8191
  if (i < 256) { int c = i >> 2, d = i & 3;
    ws[OFF_WX + i] = (d < 3) ? W1[c * 67 + d] * s1[c] : 0.f; }
  if (i < 4096) { int c = i >> 6, co = i & 63;
    ws[OFF_W1T + c * 64 + co] = W1[co * 67 + 3 + c] * s1[co]; }
  if (i < 4096) { int o = i >> 6, c = i & 63;
    float x = W2[o * 64 + c] * s2[o];
    unsigned short h = f2bf(x), lo = f2bf(x - bf2f(h));
    ((unsigned short*)(ws + OFF_W2PH))[i] = h;
    ((unsigned short*)(ws + OFF_W2PL))[i] = lo; }
  if (i < 8192) { int o = i >> 6, c = i & 63;
    float x = W3[o * 64 + c] * s3[o];
    unsigned short h = f2bf(x), lo = f2bf(x - bf2f(h));
    ((unsigned short*)(ws + OFF_W3PH))[i] = h;
    ((unsigned short*)(ws + OFF_W3PL))[i] = lo; }
}

// ---------------- xyz -> float4(x,y,z,sq); np rounding order, no fma ----------------
__global__ __launch_bounds__(256) void k_xyz4(const float* __restrict__ xyz,
                                              float* __restrict__ ws) {
  int i = blockIdx.x * 256 + threadIdx.x;          // 0..16383
  float x = xyz[i * 3], y = xyz[i * 3 + 1], z = xyz[i * 3 + 2];
  float sq = __fadd_rn(__fadd_rn(__fmul_rn(x, x), __fmul_rn(y, y)), __fmul_rn(z, z));
  ((float4*)(ws + OFF_XYZ4))[i] = make_float4(x, y, z, sq);
}

// ---------------- ball query: wave per center, LDS-staged points ----------------
__global__ __launch_bounds__(256, 2) void k_bq(const float* __restrict__ ws,
                                               int* __restrict__ idxo) {
  __shared__ float4 sxb[NPT / 2];                  // 32 KB
  int tid = threadIdx.x, lane = tid & 63;
  int center = blockIdx.x * 4 + (tid >> 6);        // 0..16383
  int b = center >> 12, n = center & 4095;
  const float4* xb = (const float4*)(ws + OFF_XYZ4) + b * NPT;
  float4 cp = xb[n];
  unsigned long long lmask = (1ull << lane) - 1ull;
  int cnt = 0, first = 0;
#pragma unroll 1
  for (int half = 0; half < 2; ++half) {
    __syncthreads();
    for (int i = tid; i < NPT / 2; i += 256) sxb[i] = xb[half * (NPT / 2) + i];
    __syncthreads();
    if (cnt >= NS) continue;                       // wave-uniform skip
    float4 p = sxb[lane];
#pragma unroll 1
    for (int ch = 0; ch < 32; ++ch) {
      float4 pn = sxb[((ch + 1) & 31) * 64 + lane];   // prefetch next chunk
      float dot = __fadd_rn(__fadd_rn(__fmul_rn(p.x, cp.x), __fmul_rn(p.y, cp.y)),
                            __fmul_rn(p.z, cp.z));
      float d2 = __fsub_rn(__fadd_rn(cp.w, p.w), __fmul_rn(2.f, dot));
      bool hit = d2 <= R2C;
      unsigned long long mk = __ballot(hit);
      int m = half * (NPT / 2) + ch * 64 + lane;
      if (mk) {
        if (cnt == 0) first = m - lane + __builtin_ctzll(mk);
        int pos = cnt + (int)__popcll(mk & lmask);
        if (hit && pos < NS) idxo[center * NS + pos] = m;
        cnt += (int)__popcll(mk);
        if (cnt >= NS) break;                      // uniform
      }
      p = pn;
    }
  }
  if (cnt < NS && lane >= cnt && lane < NS) idxo[center * NS + lane] = first;
}

// ---------------- F1s = (W1_feat @ features)*s1 + t1, [b][m][co] ----------------
__global__ __launch_bounds__(256, 4) void k_f1(
    const float* __restrict__ feat, const float* __restrict__ t1,
    const float* __restrict__ w1t, float* __restrict__ f1out) {
  int gid = blockIdx.x * 256 + threadIdx.x;        // 0..65535
  int chunk = gid >> 14, ml = gid & 16383;
  int b = ml >> 12, m = ml & 4095;
  float acc[16];
#pragma unroll
  for (int j = 0; j < 16; ++j) acc[j] = t1[chunk * 16 + j];
#pragma unroll
  for (int c = 0; c < 64; ++c) {
    float f = feat[(b * 64 + c) * NPT + m];
#pragma unroll
    for (int j = 0; j < 16; ++j)
      acc[j] = fmaf(w1t[c * 64 + chunk * 16 + j], f, acc[j]);
  }
  float* o = f1out + (size_t)(b * NPT + m) * 64 + chunk * 16;
#pragma unroll
  for (int j = 0; j < 4; ++j)
    ((float4*)o)[j] = make_float4(acc[4 * j], acc[4 * j + 1], acc[4 * j + 2], acc[4 * j + 3]);
}

// ---------------- fused MLP: layer1(VALU) + layer2/3 (bf16 Markidis MFMA) + pool ----
// block = 64 samples (2 centers), 4 waves. LDS 32KB: A1/A2 hi+lo [64][64] bf16.
// mfma_f32_16x16x32_bf16 layouts (m89-verified): A row=lane&15, k=8*(lane>>4)+j;
// B col=lane&15, same k; D col=lane&15, row=4*(lane>>4)+reg.
__global__ __launch_bounds__(256) void k_mlp(
    const float* __restrict__ ws_c, const int* __restrict__ idxp,
    const float* __restrict__ t2, const float* __restrict__ t3,
    float* __restrict__ pooledT) {
  __shared__ unsigned short A1hi[4096], A1lo[4096], A2hi[4096], A2lo[4096];
  int tid = threadIdx.x, blk = blockIdx.x;
  int l = tid & 63, w = tid >> 6;
  int col = l & 15, kg = l >> 4;

  // ---- phase A: gather + layer1 -> A1 (bf16 hi/lo, swizzled) ----
  {
    int si = tid >> 2, q = tid & 3;                // sample 0..63, 16-ch chunk
    int center = blk * 2 + (si >> 5);
    int b = center >> 12, n = center & 4095;
    int m = idxp[center * NS + (si & 31)];
    const float4* xb = (const float4*)(ws_c + OFF_XYZ4) + b * NPT;
    float4 cp = xb[n], np = xb[m];
    float rx = np.x - cp.x, ry = np.y - cp.y, rz = np.z - cp.z;
    const float4* f1p = (const float4*)(ws_c + OFF_F1S) + (size_t)(b * NPT + m) * 16 + q * 4;
    const float* wx = ws_c + OFF_WX + q * 64;
    unsigned short hi[16], lo[16];
#pragma unroll
    for (int j = 0; j < 4; ++j) {
      float4 fq = f1p[j];
      float hv[4] = {fq.x, fq.y, fq.z, fq.w};
#pragma unroll
      for (int e = 0; e < 4; ++e) {
        int cc = 4 * j + e;
        float t = fmaf(wx[cc * 4 + 2], rz, fmaf(wx[cc * 4 + 1], ry, fmaf(wx[cc * 4], rx, hv[e])));
        t = fmaxf(t, 0.f);
        hi[cc] = f2bf(t);
        lo[cc] = f2bf(t - bf2f(hi[cc]));
      }
    }
#pragma unroll
    for (int h8 = 0; h8 < 2; ++h8) {
      bf16x8 vh, vl;
#pragma unroll
      for (int e = 0; e < 8; ++e) { vh[e] = (short)hi[h8 * 8 + e]; vl[e] = (short)lo[h8 * 8 + e]; }
      *(bf16x8*)&A1hi[SWZ(si, q * 16 + 8 * h8)] = vh;
      *(bf16x8*)&A1lo[SWZ(si, q * 16 + 8 * h8)] = vl;
    }
  }
  __syncthreads();

  // ---- layer 2: M=64 N=64 K=64; wave w owns out-cols 16w..16w+15 ----
  {
    const unsigned short* w2ph = (const unsigned short*)(ws_c + OFF_W2PH);
    const unsigned short* w2pl = (const unsigned short*)(ws_c + OFF_W2PL);
    int o = 16 * w + col;
    bf16x8 bh[2], bl[2];
#pragma unroll
    for (int ks = 0; ks < 2; ++ks) {
      bh[ks] = *(const bf16x8*)&w2ph[o * 64 + 32 * ks + 8 * kg];
      bl[ks] = *(const bf16x8*)&w2pl[o * 64 + 32 * ks + 8 * kg];
    }
    float bias = t2[o];
#pragma unroll
    for (int mt = 0; mt < 4; ++mt) {
      int ar = 16 * mt + col;                      // A row = lane&15 within tile
      f32x4 acc = {bias, bias, bias, bias};
#pragma unroll
      for (int ks = 0; ks < 2; ++ks) {
        bf16x8 ah = *(const bf16x8*)&A1hi[SWZ(ar, 32 * ks + 8 * kg)];
        bf16x8 al = *(const bf16x8*)&A1lo[SWZ(ar, 32 * ks + 8 * kg)];
        acc = __builtin_amdgcn_mfma_f32_16x16x32_bf16(ah, bh[ks], acc, 0, 0, 0);
        acc = __builtin_amdgcn_mfma_f32_16x16x32_bf16(ah, bl[ks], acc, 0, 0, 0);
        acc = __builtin_amdgcn_mfma_f32_16x16x32_bf16(al, bh[ks], acc, 0, 0, 0);
      }
#pragma unroll
      for (int r = 0; r < 4; ++r) {                // D row=4*kg+r, col=16w+col
        float v = fmaxf(acc[r], 0.f);
        unsigned short h = f2bf(v), l2 = f2bf(v - bf2f(h));
        int row2 = 16 * mt + 4 * kg + r;
        A2hi[SWZ(row2, 16 * w + col)] = h;
        A2lo[SWZ(row2, 16 * w + col)] = l2;
      }
    }
  }
  __syncthreads();

  // ---- layer 3: M=64 N=128 K=64; wave w owns out-cols {16w.., 16w+64..} + pool ----
  {
    const unsigned short* w3ph = (const unsigned short*)(ws_c + OFF_W3PH);
    const unsigned short* w3pl = (const unsigned short*)(ws_c + OFF_W3PL);
    bf16x8 bh[2][2], bl[2][2];
    float bias3[2];
#pragma unroll
    for (int nts = 0; nts < 2; ++nts) {
      int o = 16 * (w + 4 * nts) + col;
      bias3[nts] = t3[o];
#pragma unroll
      for (int ks = 0; ks < 2; ++ks) {
        bh[nts][ks] = *(const bf16x8*)&w3ph[o * 64 + 32 * ks + 8 * kg];
        bl[nts][ks] = *(const bf16x8*)&w3pl[o * 64 + 32 * ks + 8 * kg];
      }
    }
    float p00 = 0.f, p01 = 0.f, p10 = 0.f, p11 = 0.f;  // [center][nts], relu=>floor 0
#pragma unroll
    for (int mt = 0; mt < 4; ++mt) {
      int ar = 16 * mt + col;
      bf16x8 ah[2], al[2];
#pragma unroll
      for (int ks = 0; ks < 2; ++ks) {
        ah[ks] = *(const bf16x8*)&A2hi[SWZ(ar, 32 * ks + 8 * kg)];
        al[ks] = *(const bf16x8*)&A2lo[SWZ(ar, 32 * ks + 8 * kg)];
      }
#pragma unroll
      for (int nts = 0; nts < 2; ++nts) {
        f32x4 acc = {bias3[nts], bias3[nts], bias3[nts], bias3[nts]};
#pragma unroll
        for (int ks = 0; ks < 2; ++ks) {
          acc = __builtin_amdgcn_mfma_f32_16x16x32_bf16(ah[ks], bh[nts][ks], acc, 0, 0, 0);
          acc = __builtin_amdgcn_mfma_f32_16x16x32_bf16(ah[ks], bl[nts][ks], acc, 0, 0, 0);
          acc = __builtin_amdgcn_mfma_f32_16x16x32_bf16(al[ks], bh[nts][ks], acc, 0, 0, 0);
        }
        float m4 = fmaxf(fmaxf(fmaxf(acc[0], acc[1]), fmaxf(acc[2], acc[3])), 0.f);
        if (mt < 2) { if (nts == 0) p00 = fmaxf(p00, m4); else p01 = fmaxf(p01, m4); }
        else        { if (nts == 0) p10 = fmaxf(p10, m4); else p11 = fmaxf(p11, m4); }
      }
    }
    // reduce over the 4 row-groups (kg): lanes l, l^16, l^32, l^48 share col
    p00 = fmaxf(p00, __shfl_xor(p00, 16)); p00 = fmaxf(p00, __shfl_xor(p00, 32));
    p01 = fmaxf(p01, __shfl_xor(p01, 16)); p01 = fmaxf(p01, __shfl_xor(p01, 32));
    p10 = fmaxf(p10, __shfl_xor(p10, 16)); p10 = fmaxf(p10, __shfl_xor(p10, 32));
    p11 = fmaxf(p11, __shfl_xor(p11, 16)); p11 = fmaxf(p11, __shfl_xor(p11, 32));
    int c2s = (l >> 5) & 1, ns = (l >> 4) & 1;
    float va = c2s ? p10 : p00, vb = c2s ? p11 : p01;
    float val = ns ? vb : va;
    int ch = 16 * (w + 4 * ns) + col;
    pooledT[(size_t)(blk * 2 + c2s) * 128 + ch] = val;
  }
}

// ---------------- (B,N,128) -> (B,128,N) transpose ----------------
__global__ __launch_bounds__(256) void k_tr(const float* __restrict__ pooledT,
                                            float* __restrict__ out) {
  __shared__ float tile[64][65];
  int b = blockIdx.z;
  int o0 = blockIdx.y * 64, n0 = blockIdx.x * 64;
  int tx = threadIdx.x & 63, ty = threadIdx.x >> 6;
#pragma unroll
  for (int j = 0; j < 16; ++j) {
    int r = j * 4 + ty;
    tile[r][tx] = pooledT[(size_t)(b * NPT + n0 + r) * 128 + o0 + tx];
  }
  __syncthreads();
#pragma unroll
  for (int j = 0; j < 16; ++j) {
    int r = j * 4 + ty;
    out[(size_t)(b * 128 + o0 + r) * NPT + n0 + tx] = tile[tx][r];
  }
}

extern "C" void kernel_launch(void* const* d_in, const int* in_sizes, int n_in,
                              void* d_out, int out_size, void* d_ws, size_t ws_size,
                              hipStream_t stream) {
  const float* xyz = (const float*)d_in[0];
  const float* feat = (const float*)d_in[1];
  const float* W1 = (const float*)d_in[2];
  const float* s1 = (const float*)d_in[3];
  const float* t1 = (const float*)d_in[4];
  const float* W2 = (const float*)d_in[5];
  const float* s2 = (const float*)d_in[6];
  const float* t2 = (const float*)d_in[7];
  const float* W3 = (const float*)d_in[8];
  const float* s3 = (const float*)d_in[9];
  const float* t3 = (const float*)d_in[10];
  float* ws = (float*)d_ws;
  int* idxp = (int*)(ws + OFF_IDX);
  float* out = (float*)d_out;

  hipMemcpyAsync(out, xyz, (size_t)NBAT * NPT * 3 * sizeof(float),
                 hipMemcpyDeviceToDevice, stream);

  k_prep<<<32, 256, 0, stream>>>(W1, s1, W2, s2, W3, s3, ws);
  k_xyz4<<<64, 256, 0, stream>>>(xyz, ws);
  k_bq<<<4096, 256, 0, stream>>>(ws, idxp);
  k_f1<<<256, 256, 0, stream>>>(feat, t1, ws + OFF_W1T, ws + OFF_F1S);
  k_mlp<<<8192, 256, 0, stream>>>(ws, idxp, t2, t3, ws + OFF_PT);
  k_tr<<<dim3(64, 2, 4), 256, 0, stream>>>(ws + OFF_PT, out + NBAT * NPT * 3);
}

// Round 9
// 247.140 us; speedup vs baseline: 1.6689x; 1.0011x over previous
//
#include <hip/hip_runtime.h>
#include <cstdint>

#define NPT   4096
#define NBAT  4
#define NS    32
#define R2C   0.04f

// ---- workspace layout (float offsets) ----
#define OFF_XYZ4 0            // B*N float4 (x,y,z,|p|^2)        65536
#define OFF_F1S  65536        // B*N*64 layer1 feature part      1048576
#define OFF_PT   1114112      // B*N*128 pooled (n-major)        2097152
#define OFF_WX   3211264      // 64*4 xyz weights *s1            256
#define OFF_W1T  3211520      // 64x64 W1 feat [c][co]*s1        4096
#define OFF_IDX  3227904      // B*N*32 int32                    524288
#define OFF_W2PH 3752192      // ushort[4096]: W2^T*s2 hi        (2048 f)
#define OFF_W2PL 3754240      // ushort[4096]: lo                (2048 f)
#define OFF_W3PH 3756288      // ushort[8192]: W3^T*s3 hi        (4096 f)
#define OFF_W3PL 3760384      // ushort[8192]: lo                (4096 f)

typedef __attribute__((ext_vector_type(8))) short bf16x8;
typedef __attribute__((ext_vector_type(4))) float f32x4;

__device__ __host__ inline unsigned short f2bf(float x) {
  unsigned u = __builtin_bit_cast(unsigned, x);
  return (unsigned short)((u + 0x7FFFu + ((u >> 16) & 1u)) >> 16);
}
__device__ inline float bf2f(unsigned short h) {
  return __uint_as_float(((unsigned)h) << 16);
}

// XOR-swizzled LDS addressing: [64 rows][64 ushorts]; 16B-granular xor of row
// (round-8 measured: SQ_LDS_BANK_CONFLICT == 0 with this scheme)
#define SWZ(row, us) (((row) << 6) + ((us) ^ (((row) & 7) << 3)))

// ---------------- weight prep: fp32 aux + bf16 hi/lo splits ----------------
__global__ __launch_bounds__(256) void k_prep(
    const float* __restrict__ W1, const float* __restrict__ s1,
    const float* __restrict__ W2, const float* __restrict__ s2,
    const float* __restrict__ W3, const float* __restrict__ s3,
    float* __restrict__ ws) {
  int i = blockIdx.x * 256 + threadIdx.x;          // 0..8191
  if (i < 256) { int c = i >> 2, d = i & 3;
    ws[OFF_WX + i] = (d < 3) ? W1[c * 67 + d] * s1[c] : 0.f; }
  if (i < 4096) { int c = i >> 6, co = i & 63;
    ws[OFF_W1T + c * 64 + co] = W1[co * 67 + 3 + c] * s1[co]; }
  if (i < 4096) { int o = i >> 6, c = i & 63;
    float x = W2[o * 64 + c] * s2[o];
    unsigned short h = f2bf(x), lo = f2bf(x - bf2f(h));
    ((unsigned short*)(ws + OFF_W2PH))[i] = h;
    ((unsigned short*)(ws + OFF_W2PL))[i] = lo; }
  if (i < 8192) { int o = i >> 6, c = i & 63;
    float x = W3[o * 64 + c] * s3[o];
    unsigned short h = f2bf(x), lo = f2bf(x - bf2f(h));
    ((unsigned short*)(ws + OFF_W3PH))[i] = h;
    ((unsigned short*)(ws + OFF_W3PL))[i] = lo; }
}

// ---------------- xyz -> float4(x,y,z,sq); np rounding order, no fma ----------------
__global__ __launch_bounds__(256) void k_xyz4(const float* __restrict__ xyz,
                                              float* __restrict__ ws) {
  int i = blockIdx.x * 256 + threadIdx.x;          // 0..16383
  float x = xyz[i * 3], y = xyz[i * 3 + 1], z = xyz[i * 3 + 2];
  float sq = __fadd_rn(__fadd_rn(__fmul_rn(x, x), __fmul_rn(y, y)), __fmul_rn(z, z));
  ((float4*)(ws + OFF_XYZ4))[i] = make_float4(x, y, z, sq);
}

// ---------------- ball query: wave per center, LDS-staged points ----------------
__global__ __launch_bounds__(256, 2) void k_bq(const float* __restrict__ ws,
                                               int* __restrict__ idxo) {
  __shared__ float4 sxb[NPT / 2];                  // 32 KB
  int tid = threadIdx.x, lane = tid & 63;
  int center = blockIdx.x * 4 + (tid >> 6);        // 0..16383
  int b = center >> 12, n = center & 4095;
  const float4* xb = (const float4*)(ws + OFF_XYZ4) + b * NPT;
  float4 cp = xb[n];
  unsigned long long lmask = (1ull << lane) - 1ull;
  int cnt = 0, first = 0;
#pragma unroll 1
  for (int half = 0; half < 2; ++half) {
    __syncthreads();
    for (int i = tid; i < NPT / 2; i += 256) sxb[i] = xb[half * (NPT / 2) + i];
    __syncthreads();
    if (cnt >= NS) continue;                       // wave-uniform skip
    float4 p = sxb[lane];
#pragma unroll 1
    for (int ch = 0; ch < 32; ++ch) {
      float4 pn = sxb[((ch + 1) & 31) * 64 + lane];   // prefetch next chunk
      float dot = __fadd_rn(__fadd_rn(__fmul_rn(p.x, cp.x), __fmul_rn(p.y, cp.y)),
                            __fmul_rn(p.z, cp.z));
      float d2 = __fsub_rn(__fadd_rn(cp.w, p.w), __fmul_rn(2.f, dot));
      bool hit = d2 <= R2C;
      unsigned long long mk = __ballot(hit);
      int m = half * (NPT / 2) + ch * 64 + lane;
      if (mk) {
        if (cnt == 0) first = m - lane + __builtin_ctzll(mk);
        int pos = cnt + (int)__popcll(mk & lmask);
        if (hit && pos < NS) idxo[center * NS + pos] = m;
        cnt += (int)__popcll(mk);
        if (cnt >= NS) break;                      // uniform
      }
      p = pn;
    }
  }
  if (cnt < NS && lane >= cnt && lane < NS) idxo[center * NS + lane] = first;
}

// ---------------- F1s = (W1_feat @ features)*s1 + t1, [b][m][co] ----------------
__global__ __launch_bounds__(256, 4) void k_f1(
    const float* __restrict__ feat, const float* __restrict__ t1,
    const float* __restrict__ w1t, float* __restrict__ f1out) {
  int gid = blockIdx.x * 256 + threadIdx.x;        // 0..65535
  int chunk = gid >> 14, ml = gid & 16383;
  int b = ml >> 12, m = ml & 4095;
  float acc[16];
#pragma unroll
  for (int j = 0; j < 16; ++j) acc[j] = t1[chunk * 16 + j];
#pragma unroll
  for (int c = 0; c < 64; ++c) {
    float f = feat[(b * 64 + c) * NPT + m];
#pragma unroll
    for (int j = 0; j < 16; ++j)
      acc[j] = fmaf(w1t[c * 64 + chunk * 16 + j], f, acc[j]);
  }
  float* o = f1out + (size_t)(b * NPT + m) * 64 + chunk * 16;
#pragma unroll
  for (int j = 0; j < 4; ++j)
    ((float4*)o)[j] = make_float4(acc[4 * j], acc[4 * j + 1], acc[4 * j + 2], acc[4 * j + 3]);
}

// ---------------- fused MLP v2: 16KB LDS (A1/A2 share buffer), hoisted weights,
// split accumulation chains. block = 64 samples (2 centers), 4 waves.
// mfma_f32_16x16x32_bf16 layouts (m89-verified): A row=lane&15, k=8*(lane>>4)+j;
// B col=lane&15, same k; D col=lane&15, row=4*(lane>>4)+reg.
__global__ __launch_bounds__(256) void k_mlp(
    const float* __restrict__ ws_c, const int* __restrict__ idxp,
    const float* __restrict__ t2, const float* __restrict__ t3,
    float* __restrict__ pooledT) {
  __shared__ __align__(16) unsigned short Hhi[4096], Hlo[4096];   // 16 KB total
  int tid = threadIdx.x, blk = blockIdx.x;
  int l = tid & 63, w = tid >> 6;
  int col = l & 15, kg = l >> 4;

  // ---- hoisted weight loads: in flight under phase A ----
  const unsigned short* w2ph = (const unsigned short*)(ws_c + OFF_W2PH);
  const unsigned short* w2pl = (const unsigned short*)(ws_c + OFF_W2PL);
  const unsigned short* w3ph = (const unsigned short*)(ws_c + OFF_W3PH);
  const unsigned short* w3pl = (const unsigned short*)(ws_c + OFF_W3PL);
  int o2 = 16 * w + col;
  bf16x8 b2h[2], b2l[2], b3h[2][2], b3l[2][2];
#pragma unroll
  for (int ks = 0; ks < 2; ++ks) {
    b2h[ks] = *(const bf16x8*)&w2ph[o2 * 64 + 32 * ks + 8 * kg];
    b2l[ks] = *(const bf16x8*)&w2pl[o2 * 64 + 32 * ks + 8 * kg];
  }
  float bias2 = t2[o2];
  float bias3[2];
#pragma unroll
  for (int nts = 0; nts < 2; ++nts) {
    int o3 = 16 * (w + 4 * nts) + col;
    bias3[nts] = t3[o3];
#pragma unroll
    for (int ks = 0; ks < 2; ++ks) {
      b3h[nts][ks] = *(const bf16x8*)&w3ph[o3 * 64 + 32 * ks + 8 * kg];
      b3l[nts][ks] = *(const bf16x8*)&w3pl[o3 * 64 + 32 * ks + 8 * kg];
    }
  }

  // ---- phase A: gather + layer1 -> H (bf16 hi/lo, swizzled) ----
  {
    int si = tid >> 2, q = tid & 3;                // sample 0..63, 16-ch chunk
    int center = blk * 2 + (si >> 5);
    int b = center >> 12, n = center & 4095;
    int m = idxp[center * NS + (si & 31)];
    const float4* xb = (const float4*)(ws_c + OFF_XYZ4) + b * NPT;
    float4 cp = xb[n], np = xb[m];
    float rx = np.x - cp.x, ry = np.y - cp.y, rz = np.z - cp.z;
    const float4* f1p = (const float4*)(ws_c + OFF_F1S) + (size_t)(b * NPT + m) * 16 + q * 4;
    const float* wx = ws_c + OFF_WX + q * 64;
    unsigned short hi[16], lo[16];
#pragma unroll
    for (int j = 0; j < 4; ++j) {
      float4 fq = f1p[j];
      float hv[4] = {fq.x, fq.y, fq.z, fq.w};
#pragma unroll
      for (int e = 0; e < 4; ++e) {
        int cc = 4 * j + e;
        float t = fmaf(wx[cc * 4 + 2], rz, fmaf(wx[cc * 4 + 1], ry, fmaf(wx[cc * 4], rx, hv[e])));
        t = fmaxf(t, 0.f);
        hi[cc] = f2bf(t);
        lo[cc] = f2bf(t - bf2f(hi[cc]));
      }
    }
#pragma unroll
    for (int h8 = 0; h8 < 2; ++h8) {
      bf16x8 vh, vl;
#pragma unroll
      for (int e = 0; e < 8; ++e) { vh[e] = (short)hi[h8 * 8 + e]; vl[e] = (short)lo[h8 * 8 + e]; }
      *(bf16x8*)&Hhi[SWZ(si, q * 16 + 8 * h8)] = vh;
      *(bf16x8*)&Hlo[SWZ(si, q * 16 + 8 * h8)] = vl;
    }
  }
  __syncthreads();

  // ---- layer 2: M=64 N=64 K=64; wave w owns out-cols 16w..16w+15.
  // Two independent MFMA chains per tile (accA: hi*hi + bias, accB: cross terms).
  float dres[4][4];
#pragma unroll
  for (int mt = 0; mt < 4; ++mt) {
    int ar = 16 * mt + col;                        // A row = lane&15 within tile
    bf16x8 ah[2], al[2];
#pragma unroll
    for (int ks = 0; ks < 2; ++ks) {
      ah[ks] = *(const bf16x8*)&Hhi[SWZ(ar, 32 * ks + 8 * kg)];
      al[ks] = *(const bf16x8*)&Hlo[SWZ(ar, 32 * ks + 8 * kg)];
    }
    f32x4 accA = {bias2, bias2, bias2, bias2};
    f32x4 accB = {0.f, 0.f, 0.f, 0.f};
    accA = __builtin_amdgcn_mfma_f32_16x16x32_bf16(ah[0], b2h[0], accA, 0, 0, 0);
    accB = __builtin_amdgcn_mfma_f32_16x16x32_bf16(ah[0], b2l[0], accB, 0, 0, 0);
    accA = __builtin_amdgcn_mfma_f32_16x16x32_bf16(ah[1], b2h[1], accA, 0, 0, 0);
    accB = __builtin_amdgcn_mfma_f32_16x16x32_bf16(ah[1], b2l[1], accB, 0, 0, 0);
    accB = __builtin_amdgcn_mfma_f32_16x16x32_bf16(al[0], b2h[0], accB, 0, 0, 0);
    accB = __builtin_amdgcn_mfma_f32_16x16x32_bf16(al[1], b2h[1], accB, 0, 0, 0);
#pragma unroll
    for (int r = 0; r < 4; ++r) dres[mt][r] = fmaxf(accA[r] + accB[r], 0.f);
  }
  __syncthreads();                                 // all waves done READING A1

  // ---- write layer-2 result (A2) over the same H buffer ----
#pragma unroll
  for (int mt = 0; mt < 4; ++mt) {
#pragma unroll
    for (int r = 0; r < 4; ++r) {                  // D row=4*kg+r, col=16w+col
      float v = dres[mt][r];
      unsigned short h = f2bf(v), l2 = f2bf(v - bf2f(h));
      int row2 = 16 * mt + 4 * kg + r;
      Hhi[SWZ(row2, o2)] = h;
      Hlo[SWZ(row2, o2)] = l2;
    }
  }
  __syncthreads();

  // ---- layer 3: M=64 N=128 K=64; wave w owns out-cols {16w.., 16w+64..} + pool ----
  {
    float p00 = 0.f, p01 = 0.f, p10 = 0.f, p11 = 0.f;  // [center][nts], relu=>floor 0
#pragma unroll
    for (int mt = 0; mt < 4; ++mt) {
      int ar = 16 * mt + col;
      bf16x8 ah[2], al[2];
#pragma unroll
      for (int ks = 0; ks < 2; ++ks) {
        ah[ks] = *(const bf16x8*)&Hhi[SWZ(ar, 32 * ks + 8 * kg)];
        al[ks] = *(const bf16x8*)&Hlo[SWZ(ar, 32 * ks + 8 * kg)];
      }
#pragma unroll
      for (int nts = 0; nts < 2; ++nts) {
        f32x4 accA = {bias3[nts], bias3[nts], bias3[nts], bias3[nts]};
        f32x4 accB = {0.f, 0.f, 0.f, 0.f};
        accA = __builtin_amdgcn_mfma_f32_16x16x32_bf16(ah[0], b3h[nts][0], accA, 0, 0, 0);
        accB = __builtin_amdgcn_mfma_f32_16x16x32_bf16(ah[0], b3l[nts][0], accB, 0, 0, 0);
        accA = __builtin_amdgcn_mfma_f32_16x16x32_bf16(ah[1], b3h[nts][1], accA, 0, 0, 0);
        accB = __builtin_amdgcn_mfma_f32_16x16x32_bf16(ah[1], b3l[nts][1], accB, 0, 0, 0);
        accB = __builtin_amdgcn_mfma_f32_16x16x32_bf16(al[0], b3h[nts][0], accB, 0, 0, 0);
        accB = __builtin_amdgcn_mfma_f32_16x16x32_bf16(al[1], b3h[nts][1], accB, 0, 0, 0);
        float m4 = fmaxf(fmaxf(fmaxf(accA[0] + accB[0], accA[1] + accB[1]),
                               fmaxf(accA[2] + accB[2], accA[3] + accB[3])), 0.f);
        if (mt < 2) { if (nts == 0) p00 = fmaxf(p00, m4); else p01 = fmaxf(p01, m4); }
        else        { if (nts == 0) p10 = fmaxf(p10, m4); else p11 = fmaxf(p11, m4); }
      }
    }
    // reduce over the 4 row-groups (kg): lanes l, l^16, l^32, l^48 share col
    p00 = fmaxf(p00, __shfl_xor(p00, 16)); p00 = fmaxf(p00, __shfl_xor(p00, 32));
    p01 = fmaxf(p01, __shfl_xor(p01, 16)); p01 = fmaxf(p01, __shfl_xor(p01, 32));
    p10 = fmaxf(p10, __shfl_xor(p10, 16)); p10 = fmaxf(p10, __shfl_xor(p10, 32));
    p11 = fmaxf(p11, __shfl_xor(p11, 16)); p11 = fmaxf(p11, __shfl_xor(p11, 32));
    int c2s = (l >> 5) & 1, ns = (l >> 4) & 1;
    float va = c2s ? p10 : p00, vb = c2s ? p11 : p01;
    float val = ns ? vb : va;
    int ch = 16 * (w + 4 * ns) + col;
    pooledT[(size_t)(blk * 2 + c2s) * 128 + ch] = val;
  }
}

// ---------------- (B,N,128) -> (B,128,N) transpose ----------------
__global__ __launch_bounds__(256) void k_tr(const float* __restrict__ pooledT,
                                            float* __restrict__ out) {
  __shared__ float tile[64][65];
  int b = blockIdx.z;
  int o0 = blockIdx.y * 64, n0 = blockIdx.x * 64;
  int tx = threadIdx.x & 63, ty = threadIdx.x >> 6;
#pragma unroll
  for (int j = 0; j < 16; ++j) {
    int r = j * 4 + ty;
    tile[r][tx] = pooledT[(size_t)(b * NPT + n0 + r) * 128 + o0 + tx];
  }
  __syncthreads();
#pragma unroll
  for (int j = 0; j < 16; ++j) {
    int r = j * 4 + ty;
    out[(size_t)(b * 128 + o0 + r) * NPT + n0 + tx] = tile[tx][r];
  }
}

extern "C" void kernel_launch(void* const* d_in, const int* in_sizes, int n_in,
                              void* d_out, int out_size, void* d_ws, size_t ws_size,
                              hipStream_t stream) {
  const float* xyz = (const float*)d_in[0];
  const float* feat = (const float*)d_in[1];
  const float* W1 = (const float*)d_in[2];
  const float* s1 = (const float*)d_in[3];
  const float* t1 = (const float*)d_in[4];
  const float* W2 = (const float*)d_in[5];
  const float* s2 = (const float*)d_in[6];
  const float* t2 = (const float*)d_in[7];
  const float* W3 = (const float*)d_in[8];
  const float* s3 = (const float*)d_in[9];
  const float* t3 = (const float*)d_in[10];
  float* ws = (float*)d_ws;
  int* idxp = (int*)(ws + OFF_IDX);
  float* out = (float*)d_out;

  hipMemcpyAsync(out, xyz, (size_t)NBAT * NPT * 3 * sizeof(float),
                 hipMemcpyDeviceToDevice, stream);

  k_prep<<<32, 256, 0, stream>>>(W1, s1, W2, s2, W3, s3, ws);
  k_xyz4<<<64, 256, 0, stream>>>(xyz, ws);
  k_bq<<<4096, 256, 0, stream>>>(ws, idxp);
  k_f1<<<256, 256, 0, stream>>>(feat, t1, ws + OFF_W1T, ws + OFF_F1S);
  k_mlp<<<8192, 256, 0, stream>>>(ws, idxp, t2, t3, ws + OFF_PT);
  k_tr<<<dim3(64, 2, 4), 256, 0, stream>>>(ws + OFF_PT, out + NBAT * NPT * 3);
}